// Round 5
// baseline (162.943 us; speedup 1.0000x reference)
//
#include <hip/hip_runtime.h>
#include <math.h>

#define NPIX 4096
#define CIN  512
#define CR   64
#define NB   16

// workspace layout (float offsets)
static const size_t Q_OFF   = 0;                                   // [16][64][4096]
static const size_t W1T_OFF = (size_t)NB * CR * NPIX;              // [512][64]
static const size_t AP_OFF  = W1T_OFF + (size_t)CIN * CR;          // [16][32][64][64]
static const size_t ATT_OFF = AP_OFF + (size_t)NB * 32 * CR * CR;  // [16][64][64]
static const size_t MT_OFF  = ATT_OFF + (size_t)NB * CR * CR;      // [16][64][512]
// total = 6,914,048 floats = 27.7 MB

#define F4(p) (*(const float4*)(p))

// K0: w1t[c][o] = w1[o][c]  (contiguous-in-o rows for staging)
__global__ __launch_bounds__(256) void k0_w1t(const float* __restrict__ w1,
                                              float* __restrict__ w1t) {
    int idx = blockIdx.x * 256 + threadIdx.x;   // 0..32767
    int c = idx >> 6, o = idx & 63;
    w1t[idx] = w1[o * CIN + c];
}

// K1: q[b][o][n] = sum_c w1[o][c] * x[b][c][n] + b1[o]
// Block tile 64o x 128px, thread tile 4o x (4+4)px. Thread's two px-quads sit
// at pxg*4 and 64+pxg*4: 16 unique 16B LDS addresses span 64 consecutive
// dwords -> 2/bank (free). Unpadded tiles, 48 KB LDS -> 3 blocks/CU.
__global__ __launch_bounds__(256) void k1_conv1(const float* __restrict__ x,
                                                const float* __restrict__ w1t,
                                                const float* __restrict__ b1,
                                                float* __restrict__ q) {
    __shared__ float xs[64 * 128];   // [kk][px]
    __shared__ float wsm[64 * 64];   // [kk][o]
    int b = blockIdx.y;
    int px0 = blockIdx.x * 128;
    int t = threadIdx.x;
    int pxg = t & 15;
    int og  = t >> 4;

    float acc[4][8];
#pragma unroll
    for (int i = 0; i < 4; i++)
#pragma unroll
        for (int j = 0; j < 8; j++) acc[i][j] = 0.f;

    for (int kc = 0; kc < 8; kc++) {
        const float* xsrc = x + ((size_t)b * CIN + kc * 64) * NPIX + px0;
        const float* wsrc = w1t + kc * 64 * 64;
#pragma unroll
        for (int j = 0; j < 8; j++) {
            int f = j * 256 + t;             // 0..2047
            int kk = f >> 5, p4 = f & 31;
            *(float4*)(xs + kk * 128 + p4 * 4) = F4(xsrc + (size_t)kk * NPIX + p4 * 4);
        }
#pragma unroll
        for (int j = 0; j < 4; j++) {
            int f = j * 256 + t;             // 0..1023
            *(float4*)(wsm + f * 4) = F4(wsrc + f * 4);
        }
        __syncthreads();
#pragma unroll 4
        for (int kk = 0; kk < 64; kk++) {
            float4 wv = F4(wsm + kk * 64 + og * 4);
            float4 x0 = F4(xs + kk * 128 + pxg * 4);
            float4 x1 = F4(xs + kk * 128 + 64 + pxg * 4);
            const float* wp = (const float*)&wv;
            const float* xp0 = (const float*)&x0;
            const float* xp1 = (const float*)&x1;
#pragma unroll
            for (int ci = 0; ci < 4; ci++) {
#pragma unroll
                for (int pi = 0; pi < 4; pi++) {
                    acc[ci][pi]     = fmaf(wp[ci], xp0[pi], acc[ci][pi]);
                    acc[ci][pi + 4] = fmaf(wp[ci], xp1[pi], acc[ci][pi + 4]);
                }
            }
        }
        __syncthreads();
    }
    float* qb = q + (size_t)b * CR * NPIX + px0 + pxg * 4;
#pragma unroll
    for (int ci = 0; ci < 4; ci++) {
        int o = og * 4 + ci;
        float bb = b1[o];
        float4 o0, o1;
        o0.x = acc[ci][0] + bb; o0.y = acc[ci][1] + bb;
        o0.z = acc[ci][2] + bb; o0.w = acc[ci][3] + bb;
        o1.x = acc[ci][4] + bb; o1.y = acc[ci][5] + bb;
        o1.z = acc[ci][6] + bb; o1.w = acc[ci][7] + bb;
        *(float4*)(qb + (size_t)o * NPIX)      = o0;
        *(float4*)(qb + (size_t)o * NPIX + 64) = o1;
    }
}

// K2a: per-(b, n-chunk of 128) partial att: ap[b][ch][c][d] = sum_{n} q[c][n] q[d][n]
__global__ __launch_bounds__(256) void k2a_att_part(const float* __restrict__ q,
                                                    float* __restrict__ ap) {
    __shared__ float qs[CR * 129];
    int b = blockIdx.y, chk = blockIdx.x;
    int t = threadIdx.x;
    const float* qb = q + (size_t)b * CR * NPIX + chk * 128;
#pragma unroll
    for (int i = 0; i < 32; i++) {
        int idx = i * 256 + t;
        int c = idx >> 7, n = idx & 127;
        qs[c * 129 + n] = qb[(size_t)c * NPIX + n];
    }
    __syncthreads();
    int c0 = (t & 15) * 4, d0 = (t >> 4) * 4;
    float acc[4][4];
#pragma unroll
    for (int a = 0; a < 4; a++)
#pragma unroll
        for (int e = 0; e < 4; e++) acc[a][e] = 0.f;
    for (int n = 0; n < 128; n++) {
        float rc[4], rd[4];
#pragma unroll
        for (int a = 0; a < 4; a++) rc[a] = qs[(c0 + a) * 129 + n];
#pragma unroll
        for (int e = 0; e < 4; e++) rd[e] = qs[(d0 + e) * 129 + n];
#pragma unroll
        for (int a = 0; a < 4; a++)
#pragma unroll
            for (int e = 0; e < 4; e++) acc[a][e] += rc[a] * rd[e];
    }
    float* app = ap + ((size_t)(b * 32 + chk) * CR) * CR;
#pragma unroll
    for (int a = 0; a < 4; a++)
#pragma unroll
        for (int e = 0; e < 4; e++)
            app[(c0 + a) * CR + d0 + e] = acc[a][e];
}

// K2b: att[b][c][d] = softmax_d( sum_ch ap[b][ch][c][d] )
__global__ __launch_bounds__(256) void k2b_softmax(const float* __restrict__ ap,
                                                   float* __restrict__ att) {
    int cq = blockIdx.x;      // 16
    int b  = blockIdx.y;      // 16
    int t = threadIdx.x;
    int lane = t & 63;        // d
    int c = cq * 4 + (t >> 6);
    float v = 0.f;
#pragma unroll 8
    for (int chk = 0; chk < 32; chk++)
        v += ap[(((size_t)(b * 32 + chk) * CR) + c) * CR + lane];
    float m = v;
#pragma unroll
    for (int s = 1; s < 64; s <<= 1) m = fmaxf(m, __shfl_xor(m, s, 64));
    float e = __expf(v - m);
    float ssum = e;
#pragma unroll
    for (int s = 1; s < 64; s <<= 1) ssum += __shfl_xor(ssum, s, 64);
    att[((size_t)b * CR + c) * CR + lane] = e / ssum;
}

// K3: Mt[b][d][c] = sum_k w2[c][k] * att[b][k][d]  (att[b] staged in LDS)
__global__ __launch_bounds__(256) void k3_m(const float* __restrict__ w2,
                                            const float* __restrict__ att,
                                            float* __restrict__ mt) {
    __shared__ float as_[CR * CR];   // [k][d], 16 KB
    int cc = blockIdx.x;   // 8 chunks of 64 c
    int b  = blockIdx.y;
    int t = threadIdx.x;
#pragma unroll
    for (int j = 0; j < 4; j++) {
        int f = j * 256 + t;
        *(float4*)(as_ + f * 4) = F4(att + (size_t)b * CR * CR + f * 4);
    }
    __syncthreads();
    int c  = cc * 64 + (t >> 2);
    int og = t & 3;                  // 16 o each
    const float* w2r = w2 + (size_t)c * CR;
    float acc[16];
#pragma unroll
    for (int j = 0; j < 16; j++) acc[j] = 0.f;
    for (int k = 0; k < CR; k++) {
        float wv = w2r[k];
#pragma unroll
        for (int j4 = 0; j4 < 4; j4++) {
            float4 av = F4(as_ + k * CR + og * 16 + j4 * 4);
            const float* app = (const float*)&av;
#pragma unroll
            for (int u = 0; u < 4; u++)
                acc[j4 * 4 + u] = fmaf(wv, app[u], acc[j4 * 4 + u]);
        }
    }
    float* mtb = mt + (size_t)b * CR * CIN + c;
#pragma unroll
    for (int j = 0; j < 16; j++) mtb[(size_t)(og * 16 + j) * CIN] = acc[j];
}

// K4: y[b][c][n] = sum_d Mt[b][d][c] * q[b][d][n] + b2[c] + x[b][c][n]
// Conflict-free split-half LDS reads; residual x prefetched into registers
// before the barrier so its HBM latency hides under the FMA loop.
__global__ __launch_bounds__(256) void k4_out(const float* __restrict__ q,
                                              const float* __restrict__ mt,
                                              const float* __restrict__ b2,
                                              const float* __restrict__ x,
                                              float* __restrict__ y) {
    __shared__ float qs[64 * 128];   // [d][px]
    __shared__ float ms[64 * 64];    // [d][c]
    int nt = blockIdx.x, cc = blockIdx.y, b = blockIdx.z;
    int px0 = nt * 128;
    int t = threadIdx.x;
    int pxg = t & 15;
    int og  = t >> 4;

    const float* qsrc = q + (size_t)b * CR * NPIX + px0;
    const float* msrc = mt + (size_t)b * CR * CIN + cc * 64;
#pragma unroll
    for (int j = 0; j < 8; j++) {
        int f = j * 256 + t;
        int kk = f >> 5, p4 = f & 31;
        *(float4*)(qs + kk * 128 + p4 * 4) = F4(qsrc + (size_t)kk * NPIX + p4 * 4);
    }
#pragma unroll
    for (int j = 0; j < 4; j++) {
        int f = j * 256 + t;
        int kk = f >> 4, o4 = f & 15;
        *(float4*)(ms + kk * 64 + o4 * 4) = F4(msrc + (size_t)kk * CIN + o4 * 4);
    }

    // prefetch residual x (independent of LDS) — in flight during FMA loop
    size_t xbase = ((size_t)b * CIN + cc * 64 + og * 4) * NPIX + px0 + pxg * 4;
    float4 xv0[4], xv1[4];
#pragma unroll
    for (int ci = 0; ci < 4; ci++) {
        xv0[ci] = F4(x + xbase + (size_t)ci * NPIX);
        xv1[ci] = F4(x + xbase + (size_t)ci * NPIX + 64);
    }
    __syncthreads();

    float acc[4][8];
#pragma unroll
    for (int i = 0; i < 4; i++)
#pragma unroll
        for (int j = 0; j < 8; j++) acc[i][j] = 0.f;
#pragma unroll 4
    for (int kk = 0; kk < 64; kk++) {
        float4 mv = F4(ms + kk * 64 + og * 4);
        float4 q0 = F4(qs + kk * 128 + pxg * 4);
        float4 q1 = F4(qs + kk * 128 + 64 + pxg * 4);
        const float* mp = (const float*)&mv;
        const float* qp0 = (const float*)&q0;
        const float* qp1 = (const float*)&q1;
#pragma unroll
        for (int ci = 0; ci < 4; ci++) {
#pragma unroll
            for (int pi = 0; pi < 4; pi++) {
                acc[ci][pi]     = fmaf(mp[ci], qp0[pi], acc[ci][pi]);
                acc[ci][pi + 4] = fmaf(mp[ci], qp1[pi], acc[ci][pi + 4]);
            }
        }
    }

#pragma unroll
    for (int ci = 0; ci < 4; ci++) {
        float bb = b2[cc * 64 + og * 4 + ci];
        size_t base = xbase + (size_t)ci * NPIX;
        float4 o0, o1;
        o0.x = acc[ci][0] + bb + xv0[ci].x; o0.y = acc[ci][1] + bb + xv0[ci].y;
        o0.z = acc[ci][2] + bb + xv0[ci].z; o0.w = acc[ci][3] + bb + xv0[ci].w;
        o1.x = acc[ci][4] + bb + xv1[ci].x; o1.y = acc[ci][5] + bb + xv1[ci].y;
        o1.z = acc[ci][6] + bb + xv1[ci].z; o1.w = acc[ci][7] + bb + xv1[ci].w;
        *(float4*)(y + base)      = o0;
        *(float4*)(y + base + 64) = o1;
    }
}

extern "C" void kernel_launch(void* const* d_in, const int* in_sizes, int n_in,
                              void* d_out, int out_size, void* d_ws, size_t ws_size,
                              hipStream_t stream) {
    const float* x  = (const float*)d_in[0];
    const float* w1 = (const float*)d_in[1];
    const float* b1 = (const float*)d_in[2];
    const float* w2 = (const float*)d_in[3];
    const float* b2 = (const float*)d_in[4];
    float* y  = (float*)d_out;
    float* ws = (float*)d_ws;

    float* q   = ws + Q_OFF;
    float* w1t = ws + W1T_OFF;
    float* ap  = ws + AP_OFF;
    float* att = ws + ATT_OFF;
    float* mt  = ws + MT_OFF;

    hipLaunchKernelGGL(k0_w1t,      dim3(128),        dim3(256), 0, stream, w1, w1t);
    hipLaunchKernelGGL(k1_conv1,    dim3(32, 16),     dim3(256), 0, stream, x, w1t, b1, q);
    hipLaunchKernelGGL(k2a_att_part,dim3(32, 16),     dim3(256), 0, stream, q, ap);
    hipLaunchKernelGGL(k2b_softmax, dim3(16, 16),     dim3(256), 0, stream, ap, att);
    hipLaunchKernelGGL(k3_m,        dim3(8, 16),      dim3(256), 0, stream, w2, att, mt);
    hipLaunchKernelGGL(k4_out,      dim3(32, 8, 16),  dim3(256), 0, stream, q, mt, b2, x, y);
}

// Round 6
// 139.082 us; speedup vs baseline: 1.1716x; 1.1716x over previous
//
#include <hip/hip_runtime.h>
#include <math.h>

#define NPIX 4096
#define CIN  512
#define CR   64
#define NB   16
#define NCHUNK 16   // k2a n-chunks (256 px each)

typedef __bf16 bf16x8 __attribute__((ext_vector_type(8)));
typedef float  f32x4  __attribute__((ext_vector_type(4)));
typedef unsigned int uint;
typedef uint   uint4v __attribute__((ext_vector_type(4)));
typedef unsigned short ushort;

// workspace layout (BYTE offsets)
static const size_t W1B_OFF = 0;                                   // bf16 [512*64]           64 KB
static const size_t Q_OFF   = W1B_OFF + 65536;                     // bf16 [16][64][4096]    8.39 MB
static const size_t QT_OFF  = Q_OFF  + (size_t)NB*CR*NPIX*2;       // bf16 [16][4096][64]    8.39 MB
static const size_t AP_OFF  = QT_OFF + (size_t)NB*NPIX*CR*2;       // f32  [16][16][64][64]  4.19 MB
static const size_t ATT_OFF = AP_OFF + (size_t)NB*NCHUNK*CR*CR*4;  // f32  [16][64][64]      0.26 MB
static const size_t MB_OFF  = ATT_OFF + (size_t)NB*CR*CR*4;        // bf16 [16][512][64]     1.05 MB
// total ~22.3 MB (< 27.7 MB proven available)

static __device__ inline uint pk_bf16(float a, float b) {
    uint r;
    asm volatile("v_cvt_pk_bf16_f32 %0, %1, %2" : "=v"(r) : "v"(a), "v"(b));
    return r;   // low 16 = a, high 16 = b
}

// K0: w1b[o][k] = bf16(w1[o][k])  (k-contiguous A-operand for k1)
__global__ __launch_bounds__(256) void k0_cast(const float* __restrict__ w1,
                                               uint* __restrict__ w1b) {
    int i = blockIdx.x * 256 + threadIdx.x;          // 0..16383 (uint = 2 bf16)
    w1b[i] = pk_bf16(w1[2 * i], w1[2 * i + 1]);
}

// K1: q[b][o][n] = sum_c w1[o][c] x[b][c][n] + b1[o]   via MFMA 16x16x32, NO LDS.
// Wave tile 64o x 16px. A-frags (w) loaded dwordx4 from L2-hot w1b; B-frags (x)
// built from 8 strided fp32 loads + cvt_pk. Stores q (bf16 [o][n]) and qt (bf16 [n][o]).
__global__ __launch_bounds__(256) void k1_conv1(const float* __restrict__ x,
                                                const ushort* __restrict__ w1b,
                                                const float* __restrict__ b1,
                                                ushort* __restrict__ q,
                                                ushort* __restrict__ qt) {
    int b = blockIdx.y;
    int t = threadIdx.x;
    int wid = t >> 6, l = t & 63;
    int lo = l & 15, kg = l >> 4;
    int px = blockIdx.x * 64 + wid * 16 + lo;
    const float* xb = x + (size_t)b * CIN * NPIX + px;

    f32x4 acc[4] = {};                                // of = 0..3 (o = of*16 + kg*4 + r)
    for (int ks = 0; ks < 16; ks++) {
        int k0 = ks * 32 + kg * 8;
        const float* xp = xb + (size_t)k0 * NPIX;
        float xv[8];
#pragma unroll
        for (int j = 0; j < 8; j++) xv[j] = xp[(size_t)j * NPIX];
        uint4v bu;
#pragma unroll
        for (int j = 0; j < 4; j++) bu[j] = pk_bf16(xv[2 * j], xv[2 * j + 1]);
        bf16x8 bf = __builtin_bit_cast(bf16x8, bu);
#pragma unroll
        for (int of = 0; of < 4; of++) {
            bf16x8 af = *(const bf16x8*)(w1b + (size_t)(of * 16 + lo) * CIN + k0);
            acc[of] = __builtin_amdgcn_mfma_f32_16x16x32_bf16(af, bf, acc[of], 0, 0, 0);
        }
    }
    // epilogue: + b1, store q[o][px] (scalar bf16) and qt[px][o] (packed pairs)
    ushort* qb  = q  + (size_t)b * CR * NPIX + px;
    ushort* qtb = qt + ((size_t)b * NPIX + px) * CR;
#pragma unroll
    for (int of = 0; of < 4; of++) {
        int o = of * 16 + kg * 4;
        float v0 = acc[of][0] + b1[o + 0];
        float v1 = acc[of][1] + b1[o + 1];
        float v2 = acc[of][2] + b1[o + 2];
        float v3 = acc[of][3] + b1[o + 3];
        uint p0 = pk_bf16(v0, v1), p1 = pk_bf16(v2, v3);
        qb[(size_t)(o + 0) * NPIX] = (ushort)(p0 & 0xffff);
        qb[(size_t)(o + 1) * NPIX] = (ushort)(p0 >> 16);
        qb[(size_t)(o + 2) * NPIX] = (ushort)(p1 & 0xffff);
        qb[(size_t)(o + 3) * NPIX] = (ushort)(p1 >> 16);
        *(uint2*)(qtb + o) = make_uint2(p0, p1);
    }
}

// K2a: ap[b][ch][c][d] = sum_{n in chunk of 256} q[c][n] q[d][n]  — pure MFMA.
// A-frag(cf) and B-frag(df) have the identical load pattern (lane&15 = c/d), so
// the same 4 loaded frags serve both operands. No LDS.
__global__ __launch_bounds__(64) void k2a_att_part(const ushort* __restrict__ q,
                                                   float* __restrict__ ap) {
    int b = blockIdx.y, ch = blockIdx.x;
    int l = threadIdx.x;
    int lo = l & 15, kg = l >> 4;
    const ushort* qb = q + (size_t)b * CR * NPIX + ch * 256;
    f32x4 acc[4][4] = {};
    for (int ks = 0; ks < 8; ks++) {
        bf16x8 fr[4];
#pragma unroll
        for (int cf = 0; cf < 4; cf++)
            fr[cf] = *(const bf16x8*)(qb + (size_t)(cf * 16 + lo) * NPIX + ks * 32 + kg * 8);
#pragma unroll
        for (int cf = 0; cf < 4; cf++)
#pragma unroll
            for (int df = 0; df < 4; df++)
                acc[cf][df] = __builtin_amdgcn_mfma_f32_16x16x32_bf16(fr[cf], fr[df], acc[cf][df], 0, 0, 0);
    }
    float* app = ap + ((size_t)(b * NCHUNK + ch) * CR) * CR;
#pragma unroll
    for (int cf = 0; cf < 4; cf++)
#pragma unroll
        for (int df = 0; df < 4; df++)
#pragma unroll
            for (int r = 0; r < 4; r++)
                app[(size_t)(cf * 16 + kg * 4 + r) * CR + df * 16 + lo] = acc[cf][df][r];
}

// K2b: att[b][c][d] = softmax_d( sum_ch ap[b][ch][c][d] )
__global__ __launch_bounds__(256) void k2b_softmax(const float* __restrict__ ap,
                                                   float* __restrict__ att) {
    int cq = blockIdx.x, b = blockIdx.y;
    int t = threadIdx.x;
    int lane = t & 63;
    int c = cq * 4 + (t >> 6);
    float v = 0.f;
#pragma unroll
    for (int ch = 0; ch < NCHUNK; ch++)
        v += ap[(((size_t)(b * NCHUNK + ch) * CR) + c) * CR + lane];
    float m = v;
#pragma unroll
    for (int s = 1; s < 64; s <<= 1) m = fmaxf(m, __shfl_xor(m, s, 64));
    float e = __expf(v - m);
    float ssum = e;
#pragma unroll
    for (int s = 1; s < 64; s <<= 1) ssum += __shfl_xor(ssum, s, 64);
    att[((size_t)b * CR + c) * CR + lane] = e / ssum;
}

// K3: mb[b][c][d] = bf16( sum_k w2[c][k] att[b][k][d] )   (d-contig A-operand for k4)
// att row address is lane-uniform -> scalar loads; w2[c][k] per-lane, L2-hot.
__global__ __launch_bounds__(256) void k3_m(const float* __restrict__ w2,
                                            const float* __restrict__ att,
                                            ushort* __restrict__ mb) {
    int b = blockIdx.y;
    int c = blockIdx.x * 256 + threadIdx.x;          // 0..511
    const float* ab  = att + (size_t)b * CR * CR;
    const float* w2r = w2 + (size_t)c * CR;
    float acc[CR];
#pragma unroll
    for (int d = 0; d < CR; d++) acc[d] = 0.f;
    for (int k = 0; k < CR; k++) {
        float wv = w2r[k];
#pragma unroll
        for (int d = 0; d < CR; d++) acc[d] = fmaf(wv, ab[k * CR + d], acc[d]);
    }
    uint* mp = (uint*)(mb + ((size_t)b * CIN + c) * CR);
#pragma unroll
    for (int i = 0; i < 8; i++) {
        uint4v u;
#pragma unroll
        for (int j = 0; j < 4; j++)
            u[j] = pk_bf16(acc[i * 8 + 2 * j], acc[i * 8 + 2 * j + 1]);
        *(uint4v*)(mp + i * 4) = u;
    }
}

// K4: y[b][c][n] = sum_d mb[c][d] qt[n][d] + b2[c] + x[b][c][n]  — 8 MFMAs + epilogue.
// grid.x = cc (fastest) so the 8 cc-blocks sharing a qt row run adjacently (L2 reuse).
__global__ __launch_bounds__(256) void k4_out(const ushort* __restrict__ qt,
                                              const ushort* __restrict__ mb,
                                              const float* __restrict__ b2,
                                              const float* __restrict__ x,
                                              float* __restrict__ y) {
    int cc = blockIdx.x, b = blockIdx.z;
    int t = threadIdx.x;
    int wid = t >> 6, l = t & 63;
    int lo = l & 15, kg = l >> 4;
    int px = blockIdx.y * 64 + wid * 16 + lo;
    const ushort* qp = qt + ((size_t)b * NPIX + px) * CR;
    const ushort* mp = mb + ((size_t)b * CIN + cc * 64) * CR;

    f32x4 acc[4] = {};
#pragma unroll
    for (int ks = 0; ks < 2; ks++) {
        bf16x8 bf = *(const bf16x8*)(qp + ks * 32 + kg * 8);
#pragma unroll
        for (int cf = 0; cf < 4; cf++) {
            bf16x8 af = *(const bf16x8*)(mp + (size_t)(cf * 16 + lo) * CR + ks * 32 + kg * 8);
            acc[cf] = __builtin_amdgcn_mfma_f32_16x16x32_bf16(af, bf, acc[cf], 0, 0, 0);
        }
    }
#pragma unroll
    for (int cf = 0; cf < 4; cf++) {
        int c = cc * 64 + cf * 16 + kg * 4;
#pragma unroll
        for (int r = 0; r < 4; r++) {
            size_t off = ((size_t)b * CIN + c + r) * NPIX + px;
            y[off] = acc[cf][r] + b2[c + r] + x[off];
        }
    }
}

extern "C" void kernel_launch(void* const* d_in, const int* in_sizes, int n_in,
                              void* d_out, int out_size, void* d_ws, size_t ws_size,
                              hipStream_t stream) {
    const float* x  = (const float*)d_in[0];
    const float* w1 = (const float*)d_in[1];
    const float* b1 = (const float*)d_in[2];
    const float* w2 = (const float*)d_in[3];
    const float* b2 = (const float*)d_in[4];
    float* y = (float*)d_out;
    char* ws = (char*)d_ws;

    uint*   w1b = (uint*)  (ws + W1B_OFF);
    ushort* q   = (ushort*)(ws + Q_OFF);
    ushort* qt  = (ushort*)(ws + QT_OFF);
    float*  ap  = (float*) (ws + AP_OFF);
    float*  att = (float*) (ws + ATT_OFF);
    ushort* mb  = (ushort*)(ws + MB_OFF);

    hipLaunchKernelGGL(k0_cast,     dim3(64),          dim3(256), 0, stream, w1, w1b);
    hipLaunchKernelGGL(k1_conv1,    dim3(64, 16),      dim3(256), 0, stream, x, (const ushort*)w1b, b1, q, qt);
    hipLaunchKernelGGL(k2a_att_part,dim3(NCHUNK, 16),  dim3(64),  0, stream, q, ap);
    hipLaunchKernelGGL(k2b_softmax, dim3(16, 16),      dim3(256), 0, stream, ap, att);
    hipLaunchKernelGGL(k3_m,        dim3(2, 16),       dim3(256), 0, stream, w2, att, mb);
    hipLaunchKernelGGL(k4_out,      dim3(8, 64, 16),   dim3(256), 0, stream, qt, mb, b2, x, y);
}

// Round 7
// 127.175 us; speedup vs baseline: 1.2812x; 1.0936x over previous
//
#include <hip/hip_runtime.h>
#include <math.h>

#define NPIX 4096
#define CIN  512
#define CR   64
#define NB   16
#define NCHUNK 32   // k2a n-chunks (128 px each)

typedef __bf16 bf16x8 __attribute__((ext_vector_type(8)));
typedef float  f32x4  __attribute__((ext_vector_type(4)));
typedef unsigned int uint;
typedef uint   uint4v __attribute__((ext_vector_type(4)));
typedef unsigned short ushort;

// workspace layout (BYTE offsets)
static const size_t W1B_OFF = 0;                                   // bf16 [512*64]           64 KB
static const size_t Q_OFF   = W1B_OFF + 65536;                     // bf16 [16][64][4096]    8.39 MB
static const size_t QT_OFF  = Q_OFF  + (size_t)NB*CR*NPIX*2;       // bf16 [16][4096][64]    8.39 MB
static const size_t AP_OFF  = QT_OFF + (size_t)NB*NPIX*CR*2;       // f32  [16][32][64][64]  8.39 MB
static const size_t ATT_OFF = AP_OFF + (size_t)NB*NCHUNK*CR*CR*4;  // f32  [16][64][64]      0.26 MB
static const size_t MB_OFF  = ATT_OFF + (size_t)NB*CR*CR*4;        // bf16 [16][512][64]     1.05 MB
// total ~26.5 MB (< 27.7 MB proven available)

static __device__ inline uint pk_bf16(float a, float b) {
    uint r;
    asm volatile("v_cvt_pk_bf16_f32 %0, %1, %2" : "=v"(r) : "v"(a), "v"(b));
    return r;   // low 16 = a, high 16 = b
}

// K0: w1b[o][k] = bf16(w1[o][k])  (k-contiguous A-operand for k1)
__global__ __launch_bounds__(256) void k0_cast(const float* __restrict__ w1,
                                               uint* __restrict__ w1b) {
    int i = blockIdx.x * 256 + threadIdx.x;          // 0..16383 (uint = 2 bf16)
    w1b[i] = pk_bf16(w1[2 * i], w1[2 * i + 1]);
}

// K1: q[b][o][n] = sum_c w1[o][c] x[b][c][n] + b1[o]  via MFMA 16x16x32, NO LDS.
// Wave tile 64o x 32px: two B-frag pixel-halves share each A-frag; unroll 2
// gives ~32 outstanding strided x loads per thread (MLP was the R6 limiter).
__global__ __launch_bounds__(256) void k1_conv1(const float* __restrict__ x,
                                                const ushort* __restrict__ w1b,
                                                const float* __restrict__ b1,
                                                ushort* __restrict__ q,
                                                ushort* __restrict__ qt) {
    int b = blockIdx.y;
    int t = threadIdx.x;
    int wid = t >> 6, l = t & 63;
    int lo = l & 15, kg = l >> 4;
    int px0 = blockIdx.x * 128 + wid * 32;
    int pxA = px0 + lo, pxB = px0 + 16 + lo;
    const float* xa = x + (size_t)b * CIN * NPIX + pxA;
    const float* xc = x + (size_t)b * CIN * NPIX + pxB;

    f32x4 accA[4] = {}, accB[4] = {};
#pragma unroll 2
    for (int ks = 0; ks < 16; ks++) {
        int k0 = ks * 32 + kg * 8;
        const float* pa = xa + (size_t)k0 * NPIX;
        const float* pc = xc + (size_t)k0 * NPIX;
        float xva[8], xvb[8];
#pragma unroll
        for (int j = 0; j < 8; j++) {
            xva[j] = pa[(size_t)j * NPIX];
            xvb[j] = pc[(size_t)j * NPIX];
        }
        bf16x8 af[4];
#pragma unroll
        for (int of = 0; of < 4; of++)
            af[of] = *(const bf16x8*)(w1b + (size_t)(of * 16 + lo) * CIN + k0);
        uint4v ba, bb;
#pragma unroll
        for (int j = 0; j < 4; j++) {
            ba[j] = pk_bf16(xva[2 * j], xva[2 * j + 1]);
            bb[j] = pk_bf16(xvb[2 * j], xvb[2 * j + 1]);
        }
        bf16x8 bfa = __builtin_bit_cast(bf16x8, ba);
        bf16x8 bfb = __builtin_bit_cast(bf16x8, bb);
#pragma unroll
        for (int of = 0; of < 4; of++) {
            accA[of] = __builtin_amdgcn_mfma_f32_16x16x32_bf16(af[of], bfa, accA[of], 0, 0, 0);
            accB[of] = __builtin_amdgcn_mfma_f32_16x16x32_bf16(af[of], bfb, accB[of], 0, 0, 0);
        }
    }
#pragma unroll
    for (int h = 0; h < 2; h++) {
        int px = h ? pxB : pxA;
        f32x4* acc = h ? accB : accA;
        ushort* qb  = q  + (size_t)b * CR * NPIX + px;
        ushort* qtb = qt + ((size_t)b * NPIX + px) * CR;
#pragma unroll
        for (int of = 0; of < 4; of++) {
            int o = of * 16 + kg * 4;
            float v0 = acc[of][0] + b1[o + 0];
            float v1 = acc[of][1] + b1[o + 1];
            float v2 = acc[of][2] + b1[o + 2];
            float v3 = acc[of][3] + b1[o + 3];
            uint p0 = pk_bf16(v0, v1), p1 = pk_bf16(v2, v3);
            qb[(size_t)(o + 0) * NPIX] = (ushort)(p0 & 0xffff);
            qb[(size_t)(o + 1) * NPIX] = (ushort)(p0 >> 16);
            qb[(size_t)(o + 2) * NPIX] = (ushort)(p1 & 0xffff);
            qb[(size_t)(o + 3) * NPIX] = (ushort)(p1 >> 16);
            *(uint2*)(qtb + o) = make_uint2(p0, p1);
        }
    }
}

// K2a: ap[b][ch][c][d] = sum_{n in 128-chunk} q[c][n] q[d][n] — pure MFMA, no LDS.
// 4 waves per block (one chunk each) -> latency overlap on the q loads.
__global__ __launch_bounds__(256) void k2a_att_part(const ushort* __restrict__ q,
                                                    float* __restrict__ ap) {
    int b = blockIdx.y;
    int ch = blockIdx.x * 4 + (threadIdx.x >> 6);
    int l = threadIdx.x & 63;
    int lo = l & 15, kg = l >> 4;
    const ushort* qb = q + (size_t)b * CR * NPIX + ch * 128;
    f32x4 acc[4][4] = {};
#pragma unroll
    for (int ks = 0; ks < 4; ks++) {
        bf16x8 fr[4];
#pragma unroll
        for (int cf = 0; cf < 4; cf++)
            fr[cf] = *(const bf16x8*)(qb + (size_t)(cf * 16 + lo) * NPIX + ks * 32 + kg * 8);
#pragma unroll
        for (int cf = 0; cf < 4; cf++)
#pragma unroll
            for (int df = 0; df < 4; df++)
                acc[cf][df] = __builtin_amdgcn_mfma_f32_16x16x32_bf16(fr[cf], fr[df], acc[cf][df], 0, 0, 0);
    }
    float* app = ap + ((size_t)(b * NCHUNK + ch) * CR) * CR;
#pragma unroll
    for (int cf = 0; cf < 4; cf++)
#pragma unroll
        for (int df = 0; df < 4; df++)
#pragma unroll
            for (int r = 0; r < 4; r++)
                app[(size_t)(cf * 16 + kg * 4 + r) * CR + df * 16 + lo] = acc[cf][df][r];
}

// K2b: att[b][c][d] = softmax_d( sum_ch ap[b][ch][c][d] )
__global__ __launch_bounds__(256) void k2b_softmax(const float* __restrict__ ap,
                                                   float* __restrict__ att) {
    int cq = blockIdx.x, b = blockIdx.y;
    int t = threadIdx.x;
    int lane = t & 63;
    int c = cq * 4 + (t >> 6);
    float v = 0.f;
#pragma unroll 8
    for (int ch = 0; ch < NCHUNK; ch++)
        v += ap[(((size_t)(b * NCHUNK + ch) * CR) + c) * CR + lane];
    float m = v;
#pragma unroll
    for (int s = 1; s < 64; s <<= 1) m = fmaxf(m, __shfl_xor(m, s, 64));
    float e = __expf(v - m);
    float ssum = e;
#pragma unroll
    for (int s = 1; s < 64; s <<= 1) ssum += __shfl_xor(ssum, s, 64);
    att[((size_t)b * CR + c) * CR + lane] = e / ssum;
}

// K3: mb[b][c][d] = bf16( sum_k w2[c][k] att[b][k][d] )  (d-contig A-operand for k4)
__global__ __launch_bounds__(256) void k3_m(const float* __restrict__ w2,
                                            const float* __restrict__ att,
                                            ushort* __restrict__ mb) {
    int b = blockIdx.y;
    int c = blockIdx.x * 256 + threadIdx.x;          // 0..511
    const float* ab  = att + (size_t)b * CR * CR;
    const float* w2r = w2 + (size_t)c * CR;
    float acc[CR];
#pragma unroll
    for (int d = 0; d < CR; d++) acc[d] = 0.f;
    for (int k = 0; k < CR; k++) {
        float wv = w2r[k];
#pragma unroll
        for (int d = 0; d < CR; d++) acc[d] = fmaf(wv, ab[k * CR + d], acc[d]);
    }
    uint* mp = (uint*)(mb + ((size_t)b * CIN + c) * CR);
#pragma unroll
    for (int i = 0; i < 8; i++) {
        uint4v u;
#pragma unroll
        for (int j = 0; j < 4; j++)
            u[j] = pk_bf16(acc[i * 8 + 2 * j], acc[i * 8 + 2 * j + 1]);
        *(uint4v*)(mp + i * 4) = u;
    }
}

// K4: y[b][c][n] = sum_d mb[c][d] qt[n][d] + b2[c] + x[b][c][n] — 8 MFMAs + epilogue.
// Load order: operand frags, then residual x (latency hides under MFMAs), then MFMA.
__global__ __launch_bounds__(256) void k4_out(const ushort* __restrict__ qt,
                                              const ushort* __restrict__ mb,
                                              const float* __restrict__ b2,
                                              const float* __restrict__ x,
                                              float* __restrict__ y) {
    int cc = blockIdx.x, b = blockIdx.z;
    int t = threadIdx.x;
    int wid = t >> 6, l = t & 63;
    int lo = l & 15, kg = l >> 4;
    int px = blockIdx.y * 64 + wid * 16 + lo;
    const ushort* qp = qt + ((size_t)b * NPIX + px) * CR;
    const ushort* mp = mb + ((size_t)b * CIN + cc * 64) * CR;

    bf16x8 bq0 = *(const bf16x8*)(qp + kg * 8);
    bf16x8 bq1 = *(const bf16x8*)(qp + 32 + kg * 8);
    bf16x8 am[4][2];
#pragma unroll
    for (int cf = 0; cf < 4; cf++) {
        am[cf][0] = *(const bf16x8*)(mp + (size_t)(cf * 16 + lo) * CR + kg * 8);
        am[cf][1] = *(const bf16x8*)(mp + (size_t)(cf * 16 + lo) * CR + 32 + kg * 8);
    }
    // residual x prefetch — issued before MFMAs, consumed after
    float xr[4][4];
#pragma unroll
    for (int cf = 0; cf < 4; cf++)
#pragma unroll
        for (int r = 0; r < 4; r++)
            xr[cf][r] = x[((size_t)b * CIN + cc * 64 + cf * 16 + kg * 4 + r) * NPIX + px];

    f32x4 acc[4] = {};
#pragma unroll
    for (int cf = 0; cf < 4; cf++) {
        acc[cf] = __builtin_amdgcn_mfma_f32_16x16x32_bf16(am[cf][0], bq0, acc[cf], 0, 0, 0);
        acc[cf] = __builtin_amdgcn_mfma_f32_16x16x32_bf16(am[cf][1], bq1, acc[cf], 0, 0, 0);
    }
#pragma unroll
    for (int cf = 0; cf < 4; cf++) {
        int c = cc * 64 + cf * 16 + kg * 4;
#pragma unroll
        for (int r = 0; r < 4; r++) {
            size_t off = ((size_t)b * CIN + c + r) * NPIX + px;
            y[off] = acc[cf][r] + b2[c + r] + xr[cf][r];
        }
    }
}

extern "C" void kernel_launch(void* const* d_in, const int* in_sizes, int n_in,
                              void* d_out, int out_size, void* d_ws, size_t ws_size,
                              hipStream_t stream) {
    const float* x  = (const float*)d_in[0];
    const float* w1 = (const float*)d_in[1];
    const float* b1 = (const float*)d_in[2];
    const float* w2 = (const float*)d_in[3];
    const float* b2 = (const float*)d_in[4];
    float* y = (float*)d_out;
    char* ws = (char*)d_ws;

    uint*   w1b = (uint*)  (ws + W1B_OFF);
    ushort* q   = (ushort*)(ws + Q_OFF);
    ushort* qt  = (ushort*)(ws + QT_OFF);
    float*  ap  = (float*) (ws + AP_OFF);
    float*  att = (float*) (ws + ATT_OFF);
    ushort* mb  = (ushort*)(ws + MB_OFF);

    hipLaunchKernelGGL(k0_cast,     dim3(64),         dim3(256), 0, stream, w1, w1b);
    hipLaunchKernelGGL(k1_conv1,    dim3(32, 16),     dim3(256), 0, stream, x, (const ushort*)w1b, b1, q, qt);
    hipLaunchKernelGGL(k2a_att_part,dim3(8, 16),      dim3(256), 0, stream, q, ap);
    hipLaunchKernelGGL(k2b_softmax, dim3(16, 16),     dim3(256), 0, stream, ap, att);
    hipLaunchKernelGGL(k3_m,        dim3(2, 16),      dim3(256), 0, stream, w2, att, mb);
    hipLaunchKernelGGL(k4_out,      dim3(8, 64, 16),  dim3(256), 0, stream, qt, mb, b2, x, y);
}

// Round 8
// 125.577 us; speedup vs baseline: 1.2976x; 1.0127x over previous
//
#include <hip/hip_runtime.h>
#include <math.h>

#define NPIX 4096
#define CIN  512
#define CR   64
#define NB   16
#define NCHUNK 32   // k2a n-chunks (128 px each)

typedef __bf16 bf16x8 __attribute__((ext_vector_type(8)));
typedef float  f32x4  __attribute__((ext_vector_type(4)));
typedef unsigned int uint;
typedef uint   uint4v __attribute__((ext_vector_type(4)));
typedef unsigned short ushort;

// workspace layout (BYTE offsets)
static const size_t W1B_OFF = 0;                                   // bf16 [512*64]           64 KB
static const size_t Q_OFF   = W1B_OFF + 65536;                     // bf16 [16][64][4096]    8.39 MB
static const size_t QT_OFF  = Q_OFF  + (size_t)NB*CR*NPIX*2;       // bf16 [16][4096][64]    8.39 MB
static const size_t AP_OFF  = QT_OFF + (size_t)NB*NPIX*CR*2;       // f32  [16][32][64][64]  8.39 MB
static const size_t ATT_OFF = AP_OFF + (size_t)NB*NCHUNK*CR*CR*4;  // f32  [16][64][64]      0.26 MB
static const size_t MB_OFF  = ATT_OFF + (size_t)NB*CR*CR*4;        // bf16 [16][512][64]     1.05 MB
// total ~26.5 MB (< 27.7 MB proven available)

static __device__ inline uint pk_bf16(float a, float b) {
    uint r;
    asm volatile("v_cvt_pk_bf16_f32 %0, %1, %2" : "=v"(r) : "v"(a), "v"(b));
    return r;   // low 16 = a, high 16 = b
}

// K0: w1b[o][k] = bf16(w1[o][k])  (k-contiguous A-operand for k1)
__global__ __launch_bounds__(256) void k0_cast(const float* __restrict__ w1,
                                               uint* __restrict__ w1b) {
    int i = blockIdx.x * 256 + threadIdx.x;          // 0..16383 (uint = 2 bf16)
    w1b[i] = pk_bf16(w1[2 * i], w1[2 * i + 1]);
}

// K1: q[b][o][n] = sum_c w1[o][c] x[b][c][n] + b1[o]  via MFMA 16x16x32, NO LDS.
// Wave tile 64o x 64px: 4 B-frags share each A-frag set; 32 outstanding
// x-dwords per thread per ks-step (MLP >> BW-latency product).
__global__ __launch_bounds__(256) void k1_conv1(const float* __restrict__ x,
                                                const ushort* __restrict__ w1b,
                                                const float* __restrict__ b1,
                                                ushort* __restrict__ q,
                                                ushort* __restrict__ qt) {
    int b = blockIdx.y;
    int t = threadIdx.x;
    int wid = t >> 6, l = t & 63;
    int lo = l & 15, kg = l >> 4;
    int px0 = blockIdx.x * 256 + wid * 64;
    const float* xb = x + (size_t)b * CIN * NPIX;

    f32x4 acc[4][4] = {};                 // [pf][of]
    for (int ks = 0; ks < 16; ks++) {
        int k0 = ks * 32 + kg * 8;
        float xv[4][8];
#pragma unroll
        for (int pf = 0; pf < 4; pf++) {
            const float* xp = xb + (size_t)k0 * NPIX + px0 + pf * 16 + lo;
#pragma unroll
            for (int j = 0; j < 8; j++) xv[pf][j] = xp[(size_t)j * NPIX];
        }
        bf16x8 af[4];
#pragma unroll
        for (int of = 0; of < 4; of++)
            af[of] = *(const bf16x8*)(w1b + (size_t)(of * 16 + lo) * CIN + k0);
#pragma unroll
        for (int pf = 0; pf < 4; pf++) {
            uint4v bu;
#pragma unroll
            for (int j = 0; j < 4; j++) bu[j] = pk_bf16(xv[pf][2 * j], xv[pf][2 * j + 1]);
            bf16x8 bf = __builtin_bit_cast(bf16x8, bu);
#pragma unroll
            for (int of = 0; of < 4; of++)
                acc[pf][of] = __builtin_amdgcn_mfma_f32_16x16x32_bf16(af[of], bf, acc[pf][of], 0, 0, 0);
        }
    }
#pragma unroll
    for (int pf = 0; pf < 4; pf++) {
        int px = px0 + pf * 16 + lo;
        ushort* qb  = q  + (size_t)b * CR * NPIX + px;
        ushort* qtb = qt + ((size_t)b * NPIX + px) * CR;
#pragma unroll
        for (int of = 0; of < 4; of++) {
            int o = of * 16 + kg * 4;
            float v0 = acc[pf][of][0] + b1[o + 0];
            float v1 = acc[pf][of][1] + b1[o + 1];
            float v2 = acc[pf][of][2] + b1[o + 2];
            float v3 = acc[pf][of][3] + b1[o + 3];
            uint p0 = pk_bf16(v0, v1), p1 = pk_bf16(v2, v3);
            qb[(size_t)(o + 0) * NPIX] = (ushort)(p0 & 0xffff);
            qb[(size_t)(o + 1) * NPIX] = (ushort)(p0 >> 16);
            qb[(size_t)(o + 2) * NPIX] = (ushort)(p1 & 0xffff);
            qb[(size_t)(o + 3) * NPIX] = (ushort)(p1 >> 16);
            *(uint2*)(qtb + o) = make_uint2(p0, p1);
        }
    }
}

// K2a: ap[b][ch][c][d] = sum_{n in 128-chunk} q[c][n] q[d][n] — pure MFMA, no LDS.
__global__ __launch_bounds__(256) void k2a_att_part(const ushort* __restrict__ q,
                                                    float* __restrict__ ap) {
    int b = blockIdx.y;
    int ch = blockIdx.x * 4 + (threadIdx.x >> 6);
    int l = threadIdx.x & 63;
    int lo = l & 15, kg = l >> 4;
    const ushort* qb = q + (size_t)b * CR * NPIX + ch * 128;
    f32x4 acc[4][4] = {};
#pragma unroll
    for (int ks = 0; ks < 4; ks++) {
        bf16x8 fr[4];
#pragma unroll
        for (int cf = 0; cf < 4; cf++)
            fr[cf] = *(const bf16x8*)(qb + (size_t)(cf * 16 + lo) * NPIX + ks * 32 + kg * 8);
#pragma unroll
        for (int cf = 0; cf < 4; cf++)
#pragma unroll
            for (int df = 0; df < 4; df++)
                acc[cf][df] = __builtin_amdgcn_mfma_f32_16x16x32_bf16(fr[cf], fr[df], acc[cf][df], 0, 0, 0);
    }
    float* app = ap + ((size_t)(b * NCHUNK + ch) * CR) * CR;
#pragma unroll
    for (int cf = 0; cf < 4; cf++)
#pragma unroll
        for (int df = 0; df < 4; df++)
#pragma unroll
            for (int r = 0; r < 4; r++)
                app[(size_t)(cf * 16 + kg * 4 + r) * CR + df * 16 + lo] = acc[cf][df][r];
}

// K2b: att[b][c][d] = softmax_d( sum_ch ap[b][ch][c][d] )
__global__ __launch_bounds__(256) void k2b_softmax(const float* __restrict__ ap,
                                                   float* __restrict__ att) {
    int cq = blockIdx.x, b = blockIdx.y;
    int t = threadIdx.x;
    int lane = t & 63;
    int c = cq * 4 + (t >> 6);
    float v = 0.f;
#pragma unroll 8
    for (int ch = 0; ch < NCHUNK; ch++)
        v += ap[(((size_t)(b * NCHUNK + ch) * CR) + c) * CR + lane];
    float m = v;
#pragma unroll
    for (int s = 1; s < 64; s <<= 1) m = fmaxf(m, __shfl_xor(m, s, 64));
    float e = __expf(v - m);
    float ssum = e;
#pragma unroll
    for (int s = 1; s < 64; s <<= 1) ssum += __shfl_xor(ssum, s, 64);
    att[((size_t)b * CR + c) * CR + lane] = e / ssum;
}

// K3: mb[b][c][d] = bf16( sum_k w2[c][k] att[b][k][d] )  (d-contig A-operand for k4)
__global__ __launch_bounds__(256) void k3_m(const float* __restrict__ w2,
                                            const float* __restrict__ att,
                                            ushort* __restrict__ mb) {
    int b = blockIdx.y;
    int c = blockIdx.x * 256 + threadIdx.x;          // 0..511
    const float* ab  = att + (size_t)b * CR * CR;
    const float* w2r = w2 + (size_t)c * CR;
    float acc[CR];
#pragma unroll
    for (int d = 0; d < CR; d++) acc[d] = 0.f;
    for (int k = 0; k < CR; k++) {
        float wv = w2r[k];
#pragma unroll
        for (int d = 0; d < CR; d++) acc[d] = fmaf(wv, ab[k * CR + d], acc[d]);
    }
    uint* mp = (uint*)(mb + ((size_t)b * CIN + c) * CR);
#pragma unroll
    for (int i = 0; i < 8; i++) {
        uint4v u;
#pragma unroll
        for (int j = 0; j < 4; j++)
            u[j] = pk_bf16(acc[i * 8 + 2 * j], acc[i * 8 + 2 * j + 1]);
        *(uint4v*)(mp + i * 4) = u;
    }
}

// K4: y[b][c][n] = sum_d mb[c][d] qt[n][d] + b2[c] + x[b][c][n] — MFMA + epilogue.
// Wave tile 64c x 32px: mb frags amortized 2x, 32 residual x-loads in flight.
__global__ __launch_bounds__(256) void k4_out(const ushort* __restrict__ qt,
                                              const ushort* __restrict__ mb,
                                              const float* __restrict__ b2,
                                              const float* __restrict__ x,
                                              float* __restrict__ y) {
    int cc = blockIdx.x, b = blockIdx.z;
    int t = threadIdx.x;
    int wid = t >> 6, l = t & 63;
    int lo = l & 15, kg = l >> 4;
    int px0 = blockIdx.y * 128 + wid * 32;
    int pxA = px0 + lo, pxB = px0 + 16 + lo;
    const ushort* qpA = qt + ((size_t)b * NPIX + pxA) * CR;
    const ushort* qpB = qt + ((size_t)b * NPIX + pxB) * CR;
    const ushort* mp = mb + ((size_t)b * CIN + cc * 64) * CR;

    bf16x8 bqA0 = *(const bf16x8*)(qpA + kg * 8);
    bf16x8 bqA1 = *(const bf16x8*)(qpA + 32 + kg * 8);
    bf16x8 bqB0 = *(const bf16x8*)(qpB + kg * 8);
    bf16x8 bqB1 = *(const bf16x8*)(qpB + 32 + kg * 8);
    bf16x8 am[4][2];
#pragma unroll
    for (int cf = 0; cf < 4; cf++) {
        am[cf][0] = *(const bf16x8*)(mp + (size_t)(cf * 16 + lo) * CR + kg * 8);
        am[cf][1] = *(const bf16x8*)(mp + (size_t)(cf * 16 + lo) * CR + 32 + kg * 8);
    }
    // residual x prefetch — issued before MFMAs, consumed after
    float xrA[4][4], xrB[4][4];
#pragma unroll
    for (int cf = 0; cf < 4; cf++)
#pragma unroll
        for (int r = 0; r < 4; r++) {
            size_t row = ((size_t)b * CIN + cc * 64 + cf * 16 + kg * 4 + r) * NPIX;
            xrA[cf][r] = x[row + pxA];
            xrB[cf][r] = x[row + pxB];
        }

    f32x4 accA[4] = {}, accB[4] = {};
#pragma unroll
    for (int cf = 0; cf < 4; cf++) {
        accA[cf] = __builtin_amdgcn_mfma_f32_16x16x32_bf16(am[cf][0], bqA0, accA[cf], 0, 0, 0);
        accA[cf] = __builtin_amdgcn_mfma_f32_16x16x32_bf16(am[cf][1], bqA1, accA[cf], 0, 0, 0);
        accB[cf] = __builtin_amdgcn_mfma_f32_16x16x32_bf16(am[cf][0], bqB0, accB[cf], 0, 0, 0);
        accB[cf] = __builtin_amdgcn_mfma_f32_16x16x32_bf16(am[cf][1], bqB1, accB[cf], 0, 0, 0);
    }
#pragma unroll
    for (int cf = 0; cf < 4; cf++) {
        int c = cc * 64 + cf * 16 + kg * 4;
#pragma unroll
        for (int r = 0; r < 4; r++) {
            size_t row = ((size_t)b * CIN + c + r) * NPIX;
            y[row + pxA] = accA[cf][r] + b2[c + r] + xrA[cf][r];
            y[row + pxB] = accB[cf][r] + b2[c + r] + xrB[cf][r];
        }
    }
}

extern "C" void kernel_launch(void* const* d_in, const int* in_sizes, int n_in,
                              void* d_out, int out_size, void* d_ws, size_t ws_size,
                              hipStream_t stream) {
    const float* x  = (const float*)d_in[0];
    const float* w1 = (const float*)d_in[1];
    const float* b1 = (const float*)d_in[2];
    const float* w2 = (const float*)d_in[3];
    const float* b2 = (const float*)d_in[4];
    float* y = (float*)d_out;
    char* ws = (char*)d_ws;

    uint*   w1b = (uint*)  (ws + W1B_OFF);
    ushort* q   = (ushort*)(ws + Q_OFF);
    ushort* qt  = (ushort*)(ws + QT_OFF);
    float*  ap  = (float*) (ws + AP_OFF);
    float*  att = (float*) (ws + ATT_OFF);
    ushort* mb  = (ushort*)(ws + MB_OFF);

    hipLaunchKernelGGL(k0_cast,     dim3(64),         dim3(256), 0, stream, w1, w1b);
    hipLaunchKernelGGL(k1_conv1,    dim3(16, 16),     dim3(256), 0, stream, x, (const ushort*)w1b, b1, q, qt);
    hipLaunchKernelGGL(k2a_att_part,dim3(8, 16),      dim3(256), 0, stream, q, ap);
    hipLaunchKernelGGL(k2b_softmax, dim3(16, 16),     dim3(256), 0, stream, ap, att);
    hipLaunchKernelGGL(k3_m,        dim3(2, 16),      dim3(256), 0, stream, w2, att, mb);
    hipLaunchKernelGGL(k4_out,      dim3(8, 32, 16),  dim3(256), 0, stream, qt, mb, b2, x, y);
}

// Round 9
// 118.537 us; speedup vs baseline: 1.3746x; 1.0594x over previous
//
#include <hip/hip_runtime.h>
#include <math.h>

#define NPIX 4096
#define CIN  512
#define CR   64
#define NB   16

typedef __bf16 bf16x8 __attribute__((ext_vector_type(8)));
typedef float  f32x4  __attribute__((ext_vector_type(4)));
typedef unsigned int uint;
typedef uint   uint4v __attribute__((ext_vector_type(4)));
typedef unsigned short ushort;

// workspace layout (BYTE offsets)
static const size_t W1B_OFF = 0;                                   // bf16 [512*64]           64 KB
static const size_t Q_OFF   = W1B_OFF + 65536;                     // bf16 [16][64][4096]    8.39 MB
static const size_t QT_OFF  = Q_OFF  + (size_t)NB*CR*NPIX*2;       // bf16 [16][4096][64]    8.39 MB
static const size_t ATT_OFF = QT_OFF + (size_t)NB*NPIX*CR*2;       // f32  [16][64][64]      0.26 MB
static const size_t MB_OFF  = ATT_OFF + (size_t)NB*CR*CR*4;        // bf16 [16][512][64]     1.05 MB
// total ~18.2 MB

static __device__ inline uint pk_bf16(float a, float b) {
    uint r;
    asm volatile("v_cvt_pk_bf16_f32 %0, %1, %2" : "=v"(r) : "v"(a), "v"(b));
    return r;   // low 16 = a, high 16 = b
}

// K0: w1b[o][k] = bf16(w1[o][k])  (k-contiguous A-operand for k1)
__global__ __launch_bounds__(256) void k0_cast(const float* __restrict__ w1,
                                               uint* __restrict__ w1b) {
    int i = blockIdx.x * 256 + threadIdx.x;          // 0..16383 (uint = 2 bf16)
    w1b[i] = pk_bf16(w1[2 * i], w1[2 * i + 1]);
}

// K1: q[b][o][n] = sum_c w1[o][c] x[b][c][n] + b1[o]  via MFMA 16x16x32, NO LDS.
// Wave tile 64o x 64px: 4 B-frags share each A-frag set; 32 outstanding
// x-dwords per thread per ks-step.
__global__ __launch_bounds__(256) void k1_conv1(const float* __restrict__ x,
                                                const ushort* __restrict__ w1b,
                                                const float* __restrict__ b1,
                                                ushort* __restrict__ q,
                                                ushort* __restrict__ qt) {
    int b = blockIdx.y;
    int t = threadIdx.x;
    int wid = t >> 6, l = t & 63;
    int lo = l & 15, kg = l >> 4;
    int px0 = blockIdx.x * 256 + wid * 64;
    const float* xb = x + (size_t)b * CIN * NPIX;

    f32x4 acc[4][4] = {};                 // [pf][of]
    for (int ks = 0; ks < 16; ks++) {
        int k0 = ks * 32 + kg * 8;
        float xv[4][8];
#pragma unroll
        for (int pf = 0; pf < 4; pf++) {
            const float* xp = xb + (size_t)k0 * NPIX + px0 + pf * 16 + lo;
#pragma unroll
            for (int j = 0; j < 8; j++) xv[pf][j] = xp[(size_t)j * NPIX];
        }
        bf16x8 af[4];
#pragma unroll
        for (int of = 0; of < 4; of++)
            af[of] = *(const bf16x8*)(w1b + (size_t)(of * 16 + lo) * CIN + k0);
#pragma unroll
        for (int pf = 0; pf < 4; pf++) {
            uint4v bu;
#pragma unroll
            for (int j = 0; j < 4; j++) bu[j] = pk_bf16(xv[pf][2 * j], xv[pf][2 * j + 1]);
            bf16x8 bf = __builtin_bit_cast(bf16x8, bu);
#pragma unroll
            for (int of = 0; of < 4; of++)
                acc[pf][of] = __builtin_amdgcn_mfma_f32_16x16x32_bf16(af[of], bf, acc[pf][of], 0, 0, 0);
        }
    }
#pragma unroll
    for (int pf = 0; pf < 4; pf++) {
        int px = px0 + pf * 16 + lo;
        ushort* qb  = q  + (size_t)b * CR * NPIX + px;
        ushort* qtb = qt + ((size_t)b * NPIX + px) * CR;
#pragma unroll
        for (int of = 0; of < 4; of++) {
            int o = of * 16 + kg * 4;
            float v0 = acc[pf][of][0] + b1[o + 0];
            float v1 = acc[pf][of][1] + b1[o + 1];
            float v2 = acc[pf][of][2] + b1[o + 2];
            float v3 = acc[pf][of][3] + b1[o + 3];
            uint p0 = pk_bf16(v0, v1), p1 = pk_bf16(v2, v3);
            qb[(size_t)(o + 0) * NPIX] = (ushort)(p0 & 0xffff);
            qb[(size_t)(o + 1) * NPIX] = (ushort)(p0 >> 16);
            qb[(size_t)(o + 2) * NPIX] = (ushort)(p1 & 0xffff);
            qb[(size_t)(o + 3) * NPIX] = (ushort)(p1 >> 16);
            *(uint2*)(qtb + o) = make_uint2(p0, p1);
        }
    }
}

// K2: att[b][c][d] = softmax_d( sum_n q[c][n] q[d][n] ) — FUSED partial+reduce+softmax.
// One block per b, 8 waves: each wave MFMAs a full 64x64 logit partial over a
// 512-px slice (symmetric-operand trick: same frags serve A and B). Partials
// to LDS ([8][64][66]: 2-way banks = free), block-reduce, wave-parallel softmax.
__global__ __launch_bounds__(512) void k2_att(const ushort* __restrict__ q,
                                              float* __restrict__ att) {
    __shared__ float part[8][64][66];    // 135 KB
    int b = blockIdx.x;
    int t = threadIdx.x;
    int w = t >> 6, l = t & 63;
    int lo = l & 15, kg = l >> 4;
    const ushort* qb = q + (size_t)b * CR * NPIX + w * 512;

    f32x4 acc[4][4] = {};
    for (int ks = 0; ks < 16; ks++) {
        bf16x8 fr[4];
#pragma unroll
        for (int cf = 0; cf < 4; cf++)
            fr[cf] = *(const bf16x8*)(qb + (size_t)(cf * 16 + lo) * NPIX + ks * 32 + kg * 8);
#pragma unroll
        for (int cf = 0; cf < 4; cf++)
#pragma unroll
            for (int df = 0; df < 4; df++)
                acc[cf][df] = __builtin_amdgcn_mfma_f32_16x16x32_bf16(fr[cf], fr[df], acc[cf][df], 0, 0, 0);
    }
#pragma unroll
    for (int cf = 0; cf < 4; cf++)
#pragma unroll
        for (int df = 0; df < 4; df++)
#pragma unroll
            for (int r = 0; r < 4; r++)
                part[w][cf * 16 + kg * 4 + r][df * 16 + lo] = acc[cf][df][r];
    __syncthreads();

#pragma unroll
    for (int i = 0; i < 8; i++) {
        int c = w * 8 + i;
        float v = 0.f;
#pragma unroll
        for (int pw = 0; pw < 8; pw++) v += part[pw][c][l];
        float m = v;
#pragma unroll
        for (int s = 1; s < 64; s <<= 1) m = fmaxf(m, __shfl_xor(m, s, 64));
        float e = __expf(v - m);
        float ssum = e;
#pragma unroll
        for (int s = 1; s < 64; s <<= 1) ssum += __shfl_xor(ssum, s, 64);
        att[((size_t)b * CR + c) * CR + l] = e / ssum;
    }
}

// K3: mb[b][c][d] = bf16( sum_k w2[c][k] att[b][k][d] )  (d-contig A-operand for k4)
// grid (8,16): thread = (c, 16-d slice) -> 4x parallelism of the old version.
__global__ __launch_bounds__(256) void k3_m(const float* __restrict__ w2,
                                            const float* __restrict__ att,
                                            ushort* __restrict__ mb) {
    int b = blockIdx.y;
    int c  = (blockIdx.x >> 2) * 256 + threadIdx.x;  // 0..511
    int dg = (blockIdx.x & 3) * 16;
    const float* ab  = att + (size_t)b * CR * CR + dg;
    const float* w2r = w2 + (size_t)c * CR;
    float acc[16];
#pragma unroll
    for (int j = 0; j < 16; j++) acc[j] = 0.f;
    for (int k = 0; k < CR; k++) {
        float wv = w2r[k];
#pragma unroll
        for (int j4 = 0; j4 < 4; j4++) {
            f32x4 av = *(const f32x4*)(ab + k * CR + j4 * 4);
#pragma unroll
            for (int u = 0; u < 4; u++)
                acc[j4 * 4 + u] = fmaf(wv, av[u], acc[j4 * 4 + u]);
        }
    }
    uint* mp = (uint*)(mb + ((size_t)b * CIN + c) * CR + dg);
#pragma unroll
    for (int i = 0; i < 8; i++)
        mp[i] = pk_bf16(acc[2 * i], acc[2 * i + 1]);
}

// K4: y[b][c][n] = sum_d mb[c][d] qt[n][d] + b2[c] + x[b][c][n] — MFMA + epilogue.
// Wave tile 64c x 32px: mb frags amortized 2x, 32 residual x-loads in flight.
__global__ __launch_bounds__(256) void k4_out(const ushort* __restrict__ qt,
                                              const ushort* __restrict__ mb,
                                              const float* __restrict__ b2,
                                              const float* __restrict__ x,
                                              float* __restrict__ y) {
    int cc = blockIdx.x, b = blockIdx.z;
    int t = threadIdx.x;
    int wid = t >> 6, l = t & 63;
    int lo = l & 15, kg = l >> 4;
    int px0 = blockIdx.y * 128 + wid * 32;
    int pxA = px0 + lo, pxB = px0 + 16 + lo;
    const ushort* qpA = qt + ((size_t)b * NPIX + pxA) * CR;
    const ushort* qpB = qt + ((size_t)b * NPIX + pxB) * CR;
    const ushort* mp = mb + ((size_t)b * CIN + cc * 64) * CR;

    bf16x8 bqA0 = *(const bf16x8*)(qpA + kg * 8);
    bf16x8 bqA1 = *(const bf16x8*)(qpA + 32 + kg * 8);
    bf16x8 bqB0 = *(const bf16x8*)(qpB + kg * 8);
    bf16x8 bqB1 = *(const bf16x8*)(qpB + 32 + kg * 8);
    bf16x8 am[4][2];
#pragma unroll
    for (int cf = 0; cf < 4; cf++) {
        am[cf][0] = *(const bf16x8*)(mp + (size_t)(cf * 16 + lo) * CR + kg * 8);
        am[cf][1] = *(const bf16x8*)(mp + (size_t)(cf * 16 + lo) * CR + 32 + kg * 8);
    }
    // residual x prefetch — issued before MFMAs, consumed after
    float xrA[4][4], xrB[4][4];
#pragma unroll
    for (int cf = 0; cf < 4; cf++)
#pragma unroll
        for (int r = 0; r < 4; r++) {
            size_t row = ((size_t)b * CIN + cc * 64 + cf * 16 + kg * 4 + r) * NPIX;
            xrA[cf][r] = x[row + pxA];
            xrB[cf][r] = x[row + pxB];
        }

    f32x4 accA[4] = {}, accB[4] = {};
#pragma unroll
    for (int cf = 0; cf < 4; cf++) {
        accA[cf] = __builtin_amdgcn_mfma_f32_16x16x32_bf16(am[cf][0], bqA0, accA[cf], 0, 0, 0);
        accA[cf] = __builtin_amdgcn_mfma_f32_16x16x32_bf16(am[cf][1], bqA1, accA[cf], 0, 0, 0);
        accB[cf] = __builtin_amdgcn_mfma_f32_16x16x32_bf16(am[cf][0], bqB0, accB[cf], 0, 0, 0);
        accB[cf] = __builtin_amdgcn_mfma_f32_16x16x32_bf16(am[cf][1], bqB1, accB[cf], 0, 0, 0);
    }
#pragma unroll
    for (int cf = 0; cf < 4; cf++) {
        int c = cc * 64 + cf * 16 + kg * 4;
#pragma unroll
        for (int r = 0; r < 4; r++) {
            size_t row = ((size_t)b * CIN + c + r) * NPIX;
            y[row + pxA] = accA[cf][r] + b2[c + r] + xrA[cf][r];
            y[row + pxB] = accB[cf][r] + b2[c + r] + xrB[cf][r];
        }
    }
}

extern "C" void kernel_launch(void* const* d_in, const int* in_sizes, int n_in,
                              void* d_out, int out_size, void* d_ws, size_t ws_size,
                              hipStream_t stream) {
    const float* x  = (const float*)d_in[0];
    const float* w1 = (const float*)d_in[1];
    const float* b1 = (const float*)d_in[2];
    const float* w2 = (const float*)d_in[3];
    const float* b2 = (const float*)d_in[4];
    float* y = (float*)d_out;
    char* ws = (char*)d_ws;

    uint*   w1b = (uint*)  (ws + W1B_OFF);
    ushort* q   = (ushort*)(ws + Q_OFF);
    ushort* qt  = (ushort*)(ws + QT_OFF);
    float*  att = (float*) (ws + ATT_OFF);
    ushort* mb  = (ushort*)(ws + MB_OFF);

    hipLaunchKernelGGL(k0_cast,  dim3(64),         dim3(256), 0, stream, w1, w1b);
    hipLaunchKernelGGL(k1_conv1, dim3(16, 16),     dim3(256), 0, stream, x, (const ushort*)w1b, b1, q, qt);
    hipLaunchKernelGGL(k2_att,   dim3(16),         dim3(512), 0, stream, q, att);
    hipLaunchKernelGGL(k3_m,     dim3(8, 16),      dim3(256), 0, stream, w2, att, mb);
    hipLaunchKernelGGL(k4_out,   dim3(8, 32, 16),  dim3(256), 0, stream, qt, mb, b2, x, y);
}

// Round 10
// 116.396 us; speedup vs baseline: 1.3999x; 1.0184x over previous
//
#include <hip/hip_runtime.h>
#include <math.h>

#define NPIX 4096
#define CIN  512
#define CR   64
#define NB   16

typedef __bf16 bf16x8 __attribute__((ext_vector_type(8)));
typedef float  f32x4  __attribute__((ext_vector_type(4)));
typedef unsigned int uint;
typedef uint   uint4v __attribute__((ext_vector_type(4)));
typedef unsigned short ushort;

// workspace layout (BYTE offsets)
static const size_t W1B_OFF = 0;                                   // bf16 [512*64]           64 KB
static const size_t Q_OFF   = W1B_OFF + 65536;                     // bf16 [16][64][4096]    8.39 MB
static const size_t QT_OFF  = Q_OFF  + (size_t)NB*CR*NPIX*2;       // qt4 granules           8.39 MB
static const size_t ATT_OFF = QT_OFF + (size_t)NB*NPIX*CR*2;       // f32  [16][64][64]      0.26 MB
static const size_t MB_OFF  = ATT_OFF + (size_t)NB*CR*CR*4;        // bf16 [16][512][64]     1.05 MB
// total ~18.2 MB

// qt4: fragment-native layout. 8-B granule (uint2) = 4 consecutive o's for one px.
// slot(b,px,of,kg,pxlo) = ((((b*256 + (px>>4))*4 + of)*4 + kg)*16 + (px&15)
// granule (of,kg) holds o in {of*16+kg*4 .. +3}; pair (kg,kg+1) = 8 consecutive o.
// k1's wave stores 64 lane-linear granules per (pf,of) -> fully coalesced 512 B.

static __device__ inline uint pk_bf16(float a, float b) {
    uint r;
    asm volatile("v_cvt_pk_bf16_f32 %0, %1, %2" : "=v"(r) : "v"(a), "v"(b));
    return r;   // low 16 = a, high 16 = b
}

// K0: w1b[o][k] = bf16(w1[o][k])  (k-contiguous A-operand for k1)
__global__ __launch_bounds__(256) void k0_cast(const float* __restrict__ w1,
                                               uint* __restrict__ w1b) {
    int i = blockIdx.x * 256 + threadIdx.x;          // 0..16383 (uint = 2 bf16)
    w1b[i] = pk_bf16(w1[2 * i], w1[2 * i + 1]);
}

#define K1_LOAD(XV, AF, KS) do {                                             \
    int k0_ = (KS) * 32 + kg * 8;                                            \
    _Pragma("unroll")                                                        \
    for (int pf = 0; pf < 4; pf++) {                                         \
        const float* xp_ = xb + (size_t)k0_ * NPIX + pf * 16;                \
        _Pragma("unroll")                                                    \
        for (int j = 0; j < 8; j++) XV[pf][j] = xp_[(size_t)j * NPIX];       \
    }                                                                        \
    _Pragma("unroll")                                                        \
    for (int of = 0; of < 4; of++)                                           \
        AF[of] = *(const bf16x8*)(w1b + (size_t)(of * 16 + lo) * CIN + k0_); \
} while (0)

#define K1_COMPUTE(XV, AF) do {                                              \
    _Pragma("unroll")                                                        \
    for (int pf = 0; pf < 4; pf++) {                                         \
        uint4v bu_;                                                          \
        _Pragma("unroll")                                                    \
        for (int j = 0; j < 4; j++)                                          \
            bu_[j] = pk_bf16(XV[pf][2 * j], XV[pf][2 * j + 1]);              \
        bf16x8 bf_ = __builtin_bit_cast(bf16x8, bu_);                        \
        _Pragma("unroll")                                                    \
        for (int of = 0; of < 4; of++)                                       \
            acc[pf][of] = __builtin_amdgcn_mfma_f32_16x16x32_bf16(           \
                AF[of], bf_, acc[pf][of], 0, 0, 0);                          \
    }                                                                        \
} while (0)

// K1: q[b][o][n] = sum_c w1[o][c] x[b][c][n] + b1[o]  via MFMA, NO LDS.
// Wave tile 64o x 64px. Explicit double-buffered prefetch pipeline: iteration
// k+1's 36 loads are issued before iteration k's cvt+MFMA consume buffer A,
// hiding HBM latency within the single resident wave per SIMD.
__global__ __launch_bounds__(256) void k1_conv1(const float* __restrict__ x,
                                                const ushort* __restrict__ w1b,
                                                const float* __restrict__ b1,
                                                ushort* __restrict__ q,
                                                uint2* __restrict__ qt4) {
    int b = blockIdx.y;
    int t = threadIdx.x;
    int wid = t >> 6, l = t & 63;
    int lo = l & 15, kg = l >> 4;
    int px0 = blockIdx.x * 256 + wid * 64;
    const float* xb = x + (size_t)b * CIN * NPIX + px0 + lo;

    f32x4 acc[4][4] = {};                 // [pf][of]
    float xvA[4][8], xvB[4][8];
    bf16x8 afA[4], afB[4];

    K1_LOAD(xvA, afA, 0);
#pragma unroll
    for (int ks2 = 0; ks2 < 8; ks2++) {
        K1_LOAD(xvB, afB, 2 * ks2 + 1);
        K1_COMPUTE(xvA, afA);
        if (ks2 < 7) K1_LOAD(xvA, afA, 2 * ks2 + 2);
        K1_COMPUTE(xvB, afB);
    }

    // epilogue: +b1; store q[o][px] (scalar) and qt4 granules (lane-linear)
#pragma unroll
    for (int pf = 0; pf < 4; pf++) {
        int px = px0 + pf * 16 + lo;
        ushort* qb = q + (size_t)b * CR * NPIX + px;
        uint2* qt4b = qt4 + (((size_t)b * 256 + (px0 >> 4) + pf) * 4) * 64 + kg * 16 + lo;
#pragma unroll
        for (int of = 0; of < 4; of++) {
            int o = of * 16 + kg * 4;
            float v0 = acc[pf][of][0] + b1[o + 0];
            float v1 = acc[pf][of][1] + b1[o + 1];
            float v2 = acc[pf][of][2] + b1[o + 2];
            float v3 = acc[pf][of][3] + b1[o + 3];
            uint p0 = pk_bf16(v0, v1), p1 = pk_bf16(v2, v3);
            qb[(size_t)(o + 0) * NPIX] = (ushort)(p0 & 0xffff);
            qb[(size_t)(o + 1) * NPIX] = (ushort)(p0 >> 16);
            qb[(size_t)(o + 2) * NPIX] = (ushort)(p1 & 0xffff);
            qb[(size_t)(o + 3) * NPIX] = (ushort)(p1 >> 16);
            qt4b[of * 64] = make_uint2(p0, p1);
        }
    }
}

// K2: att[b][c][d] = softmax_d( sum_n q[c][n] q[d][n] ) — fused, 16 waves/block.
// Each wave MFMAs a full 64x64 logit partial over a 256-px slice. Two-phase LDS
// accumulate (waves 0-7 write, 8-15 add), block-reduce 8 partials, softmax.
__global__ __launch_bounds__(1024) void k2_att(const ushort* __restrict__ q,
                                               float* __restrict__ att) {
    __shared__ float part[8][64][66];    // 135 KB
    int b = blockIdx.x;
    int t = threadIdx.x;
    int w = t >> 6, l = t & 63;
    int lo = l & 15, kg = l >> 4;
    const ushort* qb = q + (size_t)b * CR * NPIX + w * 256;

    f32x4 acc[4][4] = {};
#pragma unroll 2
    for (int ks = 0; ks < 8; ks++) {
        bf16x8 fr[4];
#pragma unroll
        for (int cf = 0; cf < 4; cf++)
            fr[cf] = *(const bf16x8*)(qb + (size_t)(cf * 16 + lo) * NPIX + ks * 32 + kg * 8);
#pragma unroll
        for (int cf = 0; cf < 4; cf++)
#pragma unroll
            for (int df = 0; df < 4; df++)
                acc[cf][df] = __builtin_amdgcn_mfma_f32_16x16x32_bf16(fr[cf], fr[df], acc[cf][df], 0, 0, 0);
    }
    if (w < 8) {
#pragma unroll
        for (int cf = 0; cf < 4; cf++)
#pragma unroll
            for (int df = 0; df < 4; df++)
#pragma unroll
                for (int r = 0; r < 4; r++)
                    part[w][cf * 16 + kg * 4 + r][df * 16 + lo] = acc[cf][df][r];
    }
    __syncthreads();
    if (w >= 8) {
        int ws = w - 8;
#pragma unroll
        for (int cf = 0; cf < 4; cf++)
#pragma unroll
            for (int df = 0; df < 4; df++)
#pragma unroll
                for (int r = 0; r < 4; r++)
                    part[ws][cf * 16 + kg * 4 + r][df * 16 + lo] += acc[cf][df][r];
    }
    __syncthreads();

#pragma unroll
    for (int i = 0; i < 4; i++) {
        int c = w * 4 + i;
        float v = 0.f;
#pragma unroll
        for (int pw = 0; pw < 8; pw++) v += part[pw][c][l];
        float m = v;
#pragma unroll
        for (int s = 1; s < 64; s <<= 1) m = fmaxf(m, __shfl_xor(m, s, 64));
        float e = __expf(v - m);
        float ssum = e;
#pragma unroll
        for (int s = 1; s < 64; s <<= 1) ssum += __shfl_xor(ssum, s, 64);
        att[((size_t)b * CR + c) * CR + l] = e / ssum;
    }
}

// K3: mb[b][c][d] = bf16( sum_k w2[c][k] att[b][k][d] )  (d-contig A-operand for k4)
__global__ __launch_bounds__(256) void k3_m(const float* __restrict__ w2,
                                            const float* __restrict__ att,
                                            ushort* __restrict__ mb) {
    int b = blockIdx.y;
    int c  = (blockIdx.x >> 2) * 256 + threadIdx.x;  // 0..511
    int dg = (blockIdx.x & 3) * 16;
    const float* ab  = att + (size_t)b * CR * CR + dg;
    const float* w2r = w2 + (size_t)c * CR;
    float acc[16];
#pragma unroll
    for (int j = 0; j < 16; j++) acc[j] = 0.f;
    for (int k = 0; k < CR; k++) {
        float wv = w2r[k];
#pragma unroll
        for (int j4 = 0; j4 < 4; j4++) {
            f32x4 av = *(const f32x4*)(ab + k * CR + j4 * 4);
#pragma unroll
            for (int u = 0; u < 4; u++)
                acc[j4 * 4 + u] = fmaf(wv, av[u], acc[j4 * 4 + u]);
        }
    }
    uint* mp = (uint*)(mb + ((size_t)b * CIN + c) * CR + dg);
#pragma unroll
    for (int i = 0; i < 8; i++)
        mp[i] = pk_bf16(acc[2 * i], acc[2 * i + 1]);
}

// K4: y[b][c][n] = sum_d mb[c][d] qt[n][d] + b2[c] + x[b][c][n] — MFMA + epilogue.
// B-frags assembled from qt4 granule pairs (two 8-B loads, same d-order as mb).
__global__ __launch_bounds__(256) void k4_out(const uint2* __restrict__ qt4,
                                              const ushort* __restrict__ mb,
                                              const float* __restrict__ b2,
                                              const float* __restrict__ x,
                                              float* __restrict__ y) {
    int cc = blockIdx.x, b = blockIdx.z;
    int t = threadIdx.x;
    int wid = t >> 6, l = t & 63;
    int lo = l & 15, kg = l >> 4;
    int px0 = blockIdx.y * 128 + wid * 32;
    int pxA = px0 + lo, pxB = px0 + 16 + lo;
    const uint2* qt4b = qt4 + (size_t)b * 65536;     // 256*4*4*16 granules per b
    const ushort* mp = mb + ((size_t)b * CIN + cc * 64) * CR;

    // B-frag from granules: frag m covers d in {m*8 .. m*8+7}
#define QT4_LD(PXHI, PXLO, M)                                                  \
    ({ int of_ = (M) >> 1, kgA_ = ((M) & 1) * 2;                               \
       const uint2* p_ = qt4b + (((size_t)(PXHI) * 4 + of_) * 4 + kgA_) * 16 + (PXLO); \
       uint2 g0_ = p_[0], g1_ = p_[16];                                        \
       uint4v u_; u_[0] = g0_.x; u_[1] = g0_.y; u_[2] = g1_.x; u_[3] = g1_.y;  \
       __builtin_bit_cast(bf16x8, u_); })

    int pxhi = px0 >> 4;
    bf16x8 bqA0 = QT4_LD(pxhi,     lo, kg);
    bf16x8 bqA1 = QT4_LD(pxhi,     lo, 4 + kg);
    bf16x8 bqB0 = QT4_LD(pxhi + 1, lo, kg);
    bf16x8 bqB1 = QT4_LD(pxhi + 1, lo, 4 + kg);
    bf16x8 am[4][2];
#pragma unroll
    for (int cf = 0; cf < 4; cf++) {
        am[cf][0] = *(const bf16x8*)(mp + (size_t)(cf * 16 + lo) * CR + kg * 8);
        am[cf][1] = *(const bf16x8*)(mp + (size_t)(cf * 16 + lo) * CR + 32 + kg * 8);
    }
    // residual x prefetch — issued before MFMAs, consumed after
    float xrA[4][4], xrB[4][4];
#pragma unroll
    for (int cf = 0; cf < 4; cf++)
#pragma unroll
        for (int r = 0; r < 4; r++) {
            size_t row = ((size_t)b * CIN + cc * 64 + cf * 16 + kg * 4 + r) * NPIX;
            xrA[cf][r] = x[row + pxA];
            xrB[cf][r] = x[row + pxB];
        }

    f32x4 accA[4] = {}, accB[4] = {};
#pragma unroll
    for (int cf = 0; cf < 4; cf++) {
        accA[cf] = __builtin_amdgcn_mfma_f32_16x16x32_bf16(am[cf][0], bqA0, accA[cf], 0, 0, 0);
        accA[cf] = __builtin_amdgcn_mfma_f32_16x16x32_bf16(am[cf][1], bqA1, accA[cf], 0, 0, 0);
        accB[cf] = __builtin_amdgcn_mfma_f32_16x16x32_bf16(am[cf][0], bqB0, accB[cf], 0, 0, 0);
        accB[cf] = __builtin_amdgcn_mfma_f32_16x16x32_bf16(am[cf][1], bqB1, accB[cf], 0, 0, 0);
    }
#pragma unroll
    for (int cf = 0; cf < 4; cf++) {
        int c = cc * 64 + cf * 16 + kg * 4;
#pragma unroll
        for (int r = 0; r < 4; r++) {
            size_t row = ((size_t)b * CIN + c + r) * NPIX;
            y[row + pxA] = accA[cf][r] + b2[c + r] + xrA[cf][r];
            y[row + pxB] = accB[cf][r] + b2[c + r] + xrB[cf][r];
        }
    }
}

extern "C" void kernel_launch(void* const* d_in, const int* in_sizes, int n_in,
                              void* d_out, int out_size, void* d_ws, size_t ws_size,
                              hipStream_t stream) {
    const float* x  = (const float*)d_in[0];
    const float* w1 = (const float*)d_in[1];
    const float* b1 = (const float*)d_in[2];
    const float* w2 = (const float*)d_in[3];
    const float* b2 = (const float*)d_in[4];
    float* y = (float*)d_out;
    char* ws = (char*)d_ws;

    uint*   w1b = (uint*)  (ws + W1B_OFF);
    ushort* q   = (ushort*)(ws + Q_OFF);
    uint2*  qt4 = (uint2*) (ws + QT_OFF);
    float*  att = (float*) (ws + ATT_OFF);
    ushort* mb  = (ushort*)(ws + MB_OFF);

    hipLaunchKernelGGL(k0_cast,  dim3(64),         dim3(256),  0, stream, w1, w1b);
    hipLaunchKernelGGL(k1_conv1, dim3(16, 16),     dim3(256),  0, stream, x, (const ushort*)w1b, b1, q, qt4);
    hipLaunchKernelGGL(k2_att,   dim3(16),         dim3(1024), 0, stream, q, att);
    hipLaunchKernelGGL(k3_m,     dim3(8, 16),      dim3(256),  0, stream, w2, att, mb);
    hipLaunchKernelGGL(k4_out,   dim3(8, 32, 16),  dim3(256),  0, stream, qt4, mb, b2, x, y);
}